// Round 16
// baseline (265.622 us; speedup 1.0000x reference)
//
#include <hip/hip_runtime.h>

using u16 = unsigned short;
using u32 = unsigned int;

typedef short bf16x8 __attribute__((ext_vector_type(8)));
typedef float f32x4 __attribute__((ext_vector_type(4)));
typedef float f32x16 __attribute__((ext_vector_type(16)));
typedef u16 u16x4 __attribute__((ext_vector_type(4)));
typedef u16 u16x8 __attribute__((ext_vector_type(8)));

__device__ __forceinline__ u16 f2b(float f) {  // RNE
  u32 u = __builtin_bit_cast(u32, f);
  u += 0x7fffu + ((u >> 16) & 1u);
  return (u16)(u >> 16);
}
__device__ __forceinline__ u16 f2b_fast(float f) {  // round-half-up: 2 VALU
  u32 u = __builtin_bit_cast(u32, f);
  return (u16)((u + 0x8000u) >> 16);
}
__device__ __forceinline__ float b2f(u16 h) {
  u32 u = ((u32)h) << 16;
  return __builtin_bit_cast(float, u);
}
__device__ __forceinline__ f32x16 zero16() {
  f32x16 v;
#pragma unroll
  for (int i = 0; i < 16; ++i) v[i] = 0.f;
  return v;
}

typedef __attribute__((address_space(1))) const u16 gas_u16;
typedef __attribute__((address_space(3))) u16 las_u16;

__device__ __forceinline__ void gload16(const u16* g, u16* l) {
  __builtin_amdgcn_global_load_lds((const gas_u16*)g, (las_u16*)l, 16, 0, 0);
}

#define MFMA16(a, b, c) __builtin_amdgcn_mfma_f32_16x16x32_bf16((a), (b), (c), 0, 0, 0)
#define MFMA32(a, b, c) __builtin_amdgcn_mfma_f32_32x32x16_bf16((a), (b), (c), 0, 0, 0)

#define LOG2E 1.4426950408889634f

// ---------------- weight / pe cast ----------------

__global__ void k_cast_wpe(const float* __restrict__ Wq, const float* __restrict__ Wk,
                           const float* __restrict__ Wv, const float* __restrict__ Wo,
                           const float* __restrict__ pe, u16* __restrict__ wbf,
                           u16* __restrict__ pet) {
  const int bx = blockIdx.x;
  if (bx < 2048) {
    int i = bx * 256 + threadIdx.x;
    int wsel = i >> 17;
    int j = (i & 131071) * 8;
    const float* src = wsel == 0 ? Wq : wsel == 1 ? Wk : wsel == 2 ? Wv : Wo;
    float s = wsel == 0 ? 0.125f * LOG2E : 1.0f;  // fold 1/sqrt(D)*log2e into Wq
    f32x4 a = *(const f32x4*)(src + j);
    f32x4 b = *(const f32x4*)(src + j + 4);
    u16x8 o;
    o[0] = f2b(a[0] * s); o[1] = f2b(a[1] * s); o[2] = f2b(a[2] * s); o[3] = f2b(a[3] * s);
    o[4] = f2b(b[0] * s); o[5] = f2b(b[1] * s); o[6] = f2b(b[2] * s); o[7] = f2b(b[3] * s);
    *(u16x8*)(wbf + (size_t)wsel * 1048576 + j) = o;
  } else {
    int i = (bx - 2048) * 256 + threadIdx.x;  // pet[j][d] = pe[d][j]
    int j = i >> 6, d = i & 63;
    pet[i] = f2b(pe[d * 1024 + j]);
  }
}

// ---------------- fused cast+projection GEMM, single-barrier dbuf + depth-2 A prefetch ----------------
// 1792 blocks: [0,256) q, [256,1024) k, [1024,1792) v.  BK=32 (r13 addresses, bit-identical).
// A fp32 stream is HBM-latency-bound: issue Aload(kt+2) at step kt into a rotating reg
// set; write As[nxt] <- f2b(A(kt+1)) whose loads were issued a full step earlier
// (flight ~2 compute phases >= HBM latency). B (L2/L3-resident weights) stays 1-deep.

__global__ __launch_bounds__(256, 3) void k_proj(const float* __restrict__ query,
                                                 const float* __restrict__ key,
                                                 const float* __restrict__ value,
                                                 const u16* __restrict__ wbf,
                                                 u16* __restrict__ qb,
                                                 u16* __restrict__ kb,
                                                 u16* __restrict__ vtb) {
  __shared__ __align__(16) u16 As[2][128 * 40];
  __shared__ __align__(16) u16 Bs[2][128 * 32];
  const int tid = threadIdx.x;
  const int lane = tid & 63;
  const int w = tid >> 6;
  const int lr = lane & 15;
  const int lg = lane >> 4;
  const int wr = w >> 1;
  const int wc = w & 1;

  const int bx = blockIdx.x;
  int seg, lbx, segsz;
  const float* X;
  const u16* W;
  if (bx < 256)       { seg = 1; lbx = bx;        segsz = 256; X = query; W = wbf; }
  else if (bx < 1024) { seg = 2; lbx = bx - 256;  segsz = 768; X = key;   W = wbf + 1048576; }
  else                { seg = 3; lbx = bx - 1024; segsz = 768; X = value; W = wbf + 2097152; }
  const int bxs = (lbx & 7) * (segsz >> 3) + (lbx >> 3);  // segment-local XCD swizzle
  const int c0 = (bxs & 7) << 7;
  const int r0 = (bxs >> 3) << 7;

  f32x4 acc[4][4];
#pragma unroll
  for (int i = 0; i < 4; ++i)
#pragma unroll
    for (int j = 0; j < 4; ++j) acc[i][j] = (f32x4){0.f, 0.f, 0.f, 0.f};

  const int srow = lane >> 2;
  const int sch = (lane & 3) * 8;
  const float* gA = X + (size_t)(r0 + w * 32 + srow) * 1024 + sch;
  const u16* gB = W + (size_t)(c0 + w * 32 + srow) * 1024 + sch;
  const int aoff = (w * 32 + srow) * 40 + sch;   // u16 offset within As[buf]
  const int boff = w * 1024;                     // u16 offset within Bs[buf]

  // two rotating A-register sets (depth-2 prefetch)
  f32x4 S0[4], S1[4];
  auto loadA = [&](f32x4(&S)[4], int kt) {
    const int k0 = kt * 32;
    S[0] = *(const f32x4*)(gA + k0);
    S[1] = *(const f32x4*)(gA + k0 + 4);
    S[2] = *(const f32x4*)(gA + k0 + 16 * 1024);
    S[3] = *(const f32x4*)(gA + k0 + 16 * 1024 + 4);
  };
  auto writeA = [&](int buf, const f32x4(&S)[4]) {
    u16x8 p0, p1;
    p0[0] = f2b(S[0][0]); p0[1] = f2b(S[0][1]); p0[2] = f2b(S[0][2]); p0[3] = f2b(S[0][3]);
    p0[4] = f2b(S[1][0]); p0[5] = f2b(S[1][1]); p0[6] = f2b(S[1][2]); p0[7] = f2b(S[1][3]);
    p1[0] = f2b(S[2][0]); p1[1] = f2b(S[2][1]); p1[2] = f2b(S[2][2]); p1[3] = f2b(S[2][3]);
    p1[4] = f2b(S[3][0]); p1[5] = f2b(S[3][1]); p1[6] = f2b(S[3][2]); p1[7] = f2b(S[3][3]);
    *(u16x8*)(&As[buf][aoff]) = p0;
    *(u16x8*)(&As[buf][aoff + 16 * 40]) = p1;
  };

  // prologue: A0, A1 in flight; write A0 into As[0]; B0 gload into Bs[0]
  loadA(S0, 0);
  loadA(S1, 1);
  gload16(gB, &Bs[0][boff]);
  gload16(gB + 16 * 1024, &Bs[0][boff + 16 * 32]);
  writeA(0, S0);  // waits on S0's loads only

  for (int kt = 0; kt < 32; ++kt) {
    const int cur = kt & 1;
    const int nxt = cur ^ 1;
    __syncthreads();  // As[cur] (written prev iter / prologue) + Bs[cur] gloads visible

    if (kt < 31) {
      const int k1 = (kt + 1) * 32;
      gload16(gB + k1, &Bs[nxt][boff]);
      gload16(gB + k1 + 16 * 1024, &Bs[nxt][boff + 16 * 32]);
    }
    if (kt < 30) {
      // reissue into the set consumed at the end of last step: S[kt&1]
      if ((kt & 1) == 0) loadA(S0, kt + 2); else loadA(S1, kt + 2);
    }

    // compute tile kt (A(kt+2) + B(kt+1) loads in flight)
    bf16x8 af[4], bfr[4];
#pragma unroll
    for (int mi = 0; mi < 4; ++mi)
      af[mi] = *(const bf16x8*)(&As[cur][(wr * 64 + mi * 16 + lr) * 40 + lg * 8]);
#pragma unroll
    for (int ci = 0; ci < 4; ++ci)
      bfr[ci] = *(const bf16x8*)(&Bs[cur][(wc * 64 + ci * 16 + lr) * 32 + lg * 8]);
#pragma unroll
    for (int mi = 0; mi < 4; ++mi)
#pragma unroll
      for (int ci = 0; ci < 4; ++ci) acc[mi][ci] = MFMA16(af[mi], bfr[ci], acc[mi][ci]);

    // write A(kt+1) (loads issued at step kt-1 -> ~2 phases of flight)
    if (kt < 31) {
      if ((kt & 1) == 0) writeA(nxt, S1); else writeA(nxt, S0);
    }
  }

  const int rbase = r0 + wr * 64;
  const int cbase = c0 + wc * 64;
  if (seg == 1) {
    // q: [b*16+h][m][64]
#pragma unroll
    for (int mi = 0; mi < 4; ++mi)
#pragma unroll
      for (int ci = 0; ci < 4; ++ci) {
        const int c = cbase + ci * 16 + lr;
        const int h = c >> 6, d = c & 63;
        const int rr = rbase + mi * 16 + lg * 4;
#pragma unroll
        for (int r = 0; r < 4; ++r) {
          const int rg = rr + r;
          const int b = rg >> 9, mm = rg & 511;
          qb[((size_t)(b * 16 + h) * 512 + mm) * 64 + d] = f2b(acc[mi][ci][r]);
        }
      }
  } else if (seg == 2) {
    // k: [b*16+h][t][64]
#pragma unroll
    for (int mi = 0; mi < 4; ++mi)
#pragma unroll
      for (int ci = 0; ci < 4; ++ci) {
        const int c = cbase + ci * 16 + lr;
        const int h = c >> 6, d = c & 63;
        const int rr = rbase + mi * 16 + lg * 4;
#pragma unroll
        for (int r = 0; r < 4; ++r) {
          const int rg = rr + r;
          const int b = rg / 1536;
          const int t = rg - b * 1536;
          kb[((size_t)(b * 16 + h) * 1536 + t) * 64 + d] = f2b(acc[mi][ci][r]);
        }
      }
  } else {
    // v^T: [b*16+h][d][1536]
#pragma unroll
    for (int mi = 0; mi < 4; ++mi)
#pragma unroll
      for (int ci = 0; ci < 4; ++ci) {
        const int c = cbase + ci * 16 + lr;
        const int h = c >> 6, d = c & 63;
        const int rr = rbase + mi * 16 + lg * 4;
        const int b = rr / 1536;
        const int t = rr - b * 1536;
        u16x4 pk;
#pragma unroll
        for (int r = 0; r < 4; ++r) pk[r] = f2b(acc[mi][ci][r]);
        *(u16x4*)(vtb + ((size_t)(b * 16 + h) * 64 + d) * 1536 + t) = pk;
      }
  }
}

// ---------------- output GEMM: d_out = ctx(bf16) * Wo^T (fp32 out) ----------------

__global__ __launch_bounds__(256, 2) void k_out(const u16* __restrict__ X,
                                                const u16* __restrict__ W,
                                                float* __restrict__ Y) {
  __shared__ __align__(16) u16 As[128 * 32];
  __shared__ __align__(16) u16 Bs[128 * 32];
  const int tid = threadIdx.x;
  const int lane = tid & 63;
  const int w = tid >> 6;
  const int lr = lane & 15;
  const int lg = lane >> 4;
  const int wr = w >> 1;
  const int wc = w & 1;
  const int bx = blockIdx.x;
  const int bxs = (bx & 7) * 32 + (bx >> 3);
  const int c0 = (bxs & 7) << 7;
  const int r0 = (bxs >> 3) << 7;

  f32x4 acc[4][4];
#pragma unroll
  for (int i = 0; i < 4; ++i)
#pragma unroll
    for (int j = 0; j < 4; ++j) acc[i][j] = (f32x4){0.f, 0.f, 0.f, 0.f};

  const int srow = lane >> 2;
  const int sch = (lane & 3) * 8;
  const u16* gA = X + (size_t)(r0 + w * 32 + srow) * 1024 + sch;
  const u16* gB = W + (size_t)(c0 + w * 32 + srow) * 1024 + sch;
  u16* lA = As + w * 32 * 32;
  u16* lB = Bs + w * 32 * 32;

  for (int kt = 0; kt < 32; ++kt) {
    const int k0 = kt * 32;
    gload16(gA + k0, lA);
    gload16(gA + k0 + 16 * 1024, lA + 16 * 32);
    gload16(gB + k0, lB);
    gload16(gB + k0 + 16 * 1024, lB + 16 * 32);
    __syncthreads();
    bf16x8 af[4], bfr[4];
#pragma unroll
    for (int mi = 0; mi < 4; ++mi)
      af[mi] = *(const bf16x8*)(As + (wr * 64 + mi * 16 + lr) * 32 + lg * 8);
#pragma unroll
    for (int ci = 0; ci < 4; ++ci)
      bfr[ci] = *(const bf16x8*)(Bs + (wc * 64 + ci * 16 + lr) * 32 + lg * 8);
#pragma unroll
    for (int mi = 0; mi < 4; ++mi)
#pragma unroll
      for (int ci = 0; ci < 4; ++ci) acc[mi][ci] = MFMA16(af[mi], bfr[ci], acc[mi][ci]);
    __syncthreads();
  }

  const int rbase = r0 + wr * 64;
  const int cbase = c0 + wc * 64;
#pragma unroll
  for (int mi = 0; mi < 4; ++mi)
#pragma unroll
    for (int ci = 0; ci < 4; ++ci) {
      const int c = cbase + ci * 16 + lr;
      const int rr = rbase + mi * 16 + lg * 4;
#pragma unroll
      for (int r = 0; r < 4; ++r) Y[(size_t)(rr + r) * 1024 + c] = acc[mi][ci][r];
    }
}

// ---------------- fused sliding-window attention (r11-exact, best measured) ----------------
// block = (head bk, 32 q-rows m0); 2048 blocks; 4 waves split the 33 t-tiles.

__global__ __launch_bounds__(256, 2) void k_attn(const u16* __restrict__ qb,
                                                 const u16* __restrict__ kb,
                                                 const u16* __restrict__ vtb,
                                                 const u16* __restrict__ pet,
                                                 u16* __restrict__ ctx) {
  __shared__ __align__(16) u16 posk[32 * 1060];  // [m][x], x = j + m (skewed)
  __shared__ __align__(16) u16 Pb[4][32 * 40];   // per-wave P staging [m][t]

  const int tid = threadIdx.x;
  const int lane = tid & 63;
  const int w = tid >> 6;
  const int ml = lane & 31;
  const int hi = lane >> 5;
  const int bx = blockIdx.x;
  const int swz = (bx & 7) * 256 + (bx >> 3);  // bijective XCD swizzle
  const int bk = swz >> 4;
  const int m0 = (swz & 15) << 5;

  const u16* Qh = qb + (size_t)bk * (512 * 64);
  const u16* Kh = kb + (size_t)bk * (1536 * 64);
  const u16* Vh = vtb + (size_t)bk * (64 * 1536);

  // Q fragments (B-operand: col=m=ml, k = ks*16 + hi*8 + i)
  bf16x8 qf[4];
#pragma unroll
  for (int ks = 0; ks < 4; ++ks)
    qf[ks] = *(const bf16x8*)(Qh + (m0 + ml) * 64 + ks * 16 + hi * 8);

  // pos prologue: pos[m][j] = q_m . pe_j via MFMA32; skew-store x = j + m
  for (int jt = 0; jt < 8; ++jt) {
    const int j0 = w * 256 + jt * 32;
    f32x16 c = zero16();
#pragma unroll
    for (int ks = 0; ks < 4; ++ks) {
      bf16x8 a = *(const bf16x8*)(pet + (j0 + ml) * 64 + ks * 16 + hi * 8);
      c = MFMA32(a, qf[ks], c);
    }
#pragma unroll
    for (int r = 0; r < 16; ++r) {
      const int tl = (r & 3) + 8 * (r >> 2) + 4 * hi;  // j_local
      posk[ml * 1060 + j0 + tl + ml] = f2b_fast(c[r]); // x = j + m
    }
  }
  __syncthreads();

  float mrun = -1e30f, lrun = 0.f;
  f32x16 oA = zero16(), oB = zero16();  // d 0..31 / 32..63

  auto loadKV = [&](bf16x8(&kf)[4], bf16x8(&vf)[2][2], int s) {
    const int t0 = m0 + s * 32;
#pragma unroll
    for (int ks = 0; ks < 4; ++ks)
      kf[ks] = *(const bf16x8*)(Kh + (t0 + ml) * 64 + ks * 16 + hi * 8);
#pragma unroll
    for (int dt = 0; dt < 2; ++dt)
#pragma unroll
      for (int kt = 0; kt < 2; ++kt)
        vf[dt][kt] = *(const bf16x8*)(Vh + (dt * 32 + ml) * 1536 + t0 + kt * 16 + hi * 8);
  };

  auto doTile = [&](int s, bf16x8(&kf)[4], bf16x8(&vf)[2][2]) {
    // QK': C'[t][m], col m=ml, rows t=(r&3)+8*(r>>2)+4*hi
    __builtin_amdgcn_s_setprio(1);
    f32x16 sc = zero16();
#pragma unroll
    for (int ks = 0; ks < 4; ++ks) sc = MFMA32(kf[ks], qf[ks], sc);
    __builtin_amdgcn_s_setprio(0);

    // pos add at x = s*32 + tl (skew cancels m); explicit edge mask on s in {0,32}
    const bool edge = (s == 0) | (s == 32);
#pragma unroll
    for (int q = 0; q < 4; ++q) {
      const u16x4 pk = *(const u16x4*)(posk + ml * 1060 + s * 32 + q * 8 + hi * 4);
#pragma unroll
      for (int r0 = 0; r0 < 4; ++r0) {
        const int r = q * 4 + r0;
        float v = sc[r] + b2f(pk[r0]);
        if (edge) {
          const int j = s * 32 + q * 8 + hi * 4 + r0 - ml;
          v = (j >= 0 && j < 1024) ? v : -1e30f;
        }
        sc[r] = v;
      }
    }

    // row max: in-lane tree + shfl_xor(32)
    float a0 = fmaxf(fmaxf(sc[0], sc[1]), fmaxf(sc[2], sc[3]));
    float a1 = fmaxf(fmaxf(sc[4], sc[5]), fmaxf(sc[6], sc[7]));
    float a2 = fmaxf(fmaxf(sc[8], sc[9]), fmaxf(sc[10], sc[11]));
    float a3 = fmaxf(fmaxf(sc[12], sc[13]), fmaxf(sc[14], sc[15]));
    float pmax = fmaxf(fmaxf(a0, a1), fmaxf(a2, a3));
    pmax = fmaxf(pmax, __shfl_xor(pmax, 32));

    // exact deferred rescale: when no column max grew, scale == 1.0 -> skip
    if (__ballot(pmax > mrun)) {
      const float mn = fmaxf(mrun, pmax);
      const float scale = __builtin_amdgcn_exp2f(mrun - mn);
      lrun *= scale;
      mrun = mn;
#pragma unroll
      for (int r = 0; r < 16; ++r) { oA[r] *= scale; oB[r] *= scale; }
    }

#pragma unroll
    for (int r = 0; r < 16; ++r) sc[r] = __builtin_amdgcn_exp2f(sc[r] - mrun);
    float s0 = (sc[0] + sc[1]) + (sc[2] + sc[3]);
    float s1 = (sc[4] + sc[5]) + (sc[6] + sc[7]);
    float s2 = (sc[8] + sc[9]) + (sc[10] + sc[11]);
    float s3 = (sc[12] + sc[13]) + (sc[14] + sc[15]);
    float rs = (s0 + s1) + (s2 + s3);
    rs += __shfl_xor(rs, 32);
    lrun += rs;

    // P staging via LDS (u16-family stores + fence — HW-validated path)
#pragma unroll
    for (int q = 0; q < 4; ++q) {
      u16x4 pk;
#pragma unroll
      for (int r0 = 0; r0 < 4; ++r0) pk[r0] = f2b_fast(sc[q * 4 + r0]);
      *(u16x4*)(&Pb[w][ml * 40 + q * 8 + hi * 4]) = pk;
    }
    asm volatile("" ::: "memory");
    bf16x8 pb0 = *(const bf16x8*)(&Pb[w][ml * 40 + hi * 8]);
    bf16x8 pb1 = *(const bf16x8*)(&Pb[w][ml * 40 + 16 + hi * 8]);

    __builtin_amdgcn_s_setprio(1);
    oA = MFMA32(vf[0][0], pb0, oA);
    oB = MFMA32(vf[1][0], pb0, oB);
    oA = MFMA32(vf[0][1], pb1, oA);
    oB = MFMA32(vf[1][1], pb1, oB);
    __builtin_amdgcn_s_setprio(0);
  };

  // main loop: wave w owns tiles s = w, w+4, ..., <=32; K/V double-buffered
  bf16x8 kfA[4], kfB[4], vfA[2][2], vfB[2][2];
  loadKV(kfA, vfA, w);
  for (int s = w;;) {
    const int sn = s + 4;
    if (sn <= 32) loadKV(kfB, vfB, sn);
    doTile(s, kfA, vfA);
    if (sn > 32) break;
    s = sn;
    const int sn2 = s + 4;
    if (sn2 <= 32) loadKV(kfA, vfA, sn2);
    doTile(s, kfB, vfB);
    if (sn2 > 32) break;
    s = sn2;
  }

  // merge the 4 wave-partials (scratch overlays posk; stride 68 avoids conflicts)
  __syncthreads();
  float* mO = (float*)posk;         // [4][32][68]
  float* mM = mO + 4 * 32 * 68;     // [4][32]
  float* mL = mM + 128;             // [4][32]
#pragma unroll
  for (int q = 0; q < 4; ++q) {
    *(f32x4*)(mO + (w * 32 + ml) * 68 + q * 8 + hi * 4) =
        (f32x4){oA[4 * q], oA[4 * q + 1], oA[4 * q + 2], oA[4 * q + 3]};
    *(f32x4*)(mO + (w * 32 + ml) * 68 + 32 + q * 8 + hi * 4) =
        (f32x4){oB[4 * q], oB[4 * q + 1], oB[4 * q + 2], oB[4 * q + 3]};
  }
  if (hi == 0) {
    mM[w * 32 + ml] = mrun;
    mL[w * 32 + ml] = lrun;
  }
  __syncthreads();

  const int m = tid >> 3;
  const int d0 = (tid & 7) * 8;
  float mw4[4], lw4[4], M = -3e38f;
#pragma unroll
  for (int i = 0; i < 4; ++i) {
    mw4[i] = mM[i * 32 + m];
    lw4[i] = mL[i * 32 + m];
    M = fmaxf(M, mw4[i]);
  }
  float den = 0.f;
  float o[8] = {0.f, 0.f, 0.f, 0.f, 0.f, 0.f, 0.f, 0.f};
#pragma unroll
  for (int i = 0; i < 4; ++i) {
    const float e = __builtin_amdgcn_exp2f(mw4[i] - M);
    den += lw4[i] * e;
    f32x4 a = *(const f32x4*)(mO + (i * 32 + m) * 68 + d0);
    f32x4 b = *(const f32x4*)(mO + (i * 32 + m) * 68 + d0 + 4);
#pragma unroll
    for (int r = 0; r < 4; ++r) {
      o[r] += e * a[r];
      o[4 + r] += e * b[r];
    }
  }
  const float inv = 1.f / den;
  u16x8 ov;
#pragma unroll
  for (int i = 0; i < 8; ++i) ov[i] = f2b_fast(o[i] * inv);
  const int b_ = bk >> 4, h = bk & 15;
  *(u16x8*)(ctx + ((size_t)(b_ * 512 + m0 + m)) * 1024 + h * 64 + d0) = ov;
}

// ---------------- launch ----------------

extern "C" void kernel_launch(void* const* d_in, const int* in_sizes, int n_in,
                              void* d_out, int out_size, void* d_ws, size_t ws_size,
                              hipStream_t stream) {
  (void)in_sizes; (void)n_in; (void)out_size; (void)ws_size;
  const float* query = (const float*)d_in[0];
  const float* key   = (const float*)d_in[1];
  const float* value = (const float*)d_in[2];
  const float* pe    = (const float*)d_in[3];
  const float* Wq    = (const float*)d_in[4];
  const float* Wk    = (const float*)d_in[5];
  const float* Wv    = (const float*)d_in[6];
  const float* Wo    = (const float*)d_in[7];

  u16* wbf = (u16*)d_ws;             // 4 x 1M
  u16* pet = wbf + 4194304;          // 65536
  u16* qb  = pet + 65536;            // 4194304
  u16* kb  = qb + 4194304;           // 12582912
  u16* vtb = kb + 12582912;          // 12582912
  u16* ctx = vtb + 12582912;         // 4194304

  k_cast_wpe<<<2304, 256, 0, stream>>>(Wq, Wk, Wv, Wo, pe, wbf, pet);
  k_proj<<<1792, 256, 0, stream>>>(query, key, value, wbf, qb, kb, vtb);
  k_attn<<<2048, 256, 0, stream>>>(qb, kb, vtb, pet, ctx);
  k_out<<<256, 256, 0, stream>>>(ctx, wbf + 3145728, (float*)d_out);
}

// Round 17
// 208.834 us; speedup vs baseline: 1.2719x; 1.2719x over previous
//
#include <hip/hip_runtime.h>

using u16 = unsigned short;
using u32 = unsigned int;

typedef short bf16x8 __attribute__((ext_vector_type(8)));
typedef float f32x4 __attribute__((ext_vector_type(4)));
typedef float f32x16 __attribute__((ext_vector_type(16)));
typedef u16 u16x4 __attribute__((ext_vector_type(4)));
typedef u16 u16x8 __attribute__((ext_vector_type(8)));

__device__ __forceinline__ u16 f2b(float f) {  // RNE
  u32 u = __builtin_bit_cast(u32, f);
  u += 0x7fffu + ((u >> 16) & 1u);
  return (u16)(u >> 16);
}
__device__ __forceinline__ u16 f2b_fast(float f) {  // round-half-up: 2 VALU
  u32 u = __builtin_bit_cast(u32, f);
  return (u16)((u + 0x8000u) >> 16);
}
__device__ __forceinline__ float b2f(u16 h) {
  u32 u = ((u32)h) << 16;
  return __builtin_bit_cast(float, u);
}
__device__ __forceinline__ f32x16 zero16() {
  f32x16 v;
#pragma unroll
  for (int i = 0; i < 16; ++i) v[i] = 0.f;
  return v;
}

typedef __attribute__((address_space(1))) const u16 gas_u16;
typedef __attribute__((address_space(3))) u16 las_u16;

__device__ __forceinline__ void gload16(const u16* g, u16* l) {
  __builtin_amdgcn_global_load_lds((const gas_u16*)g, (las_u16*)l, 16, 0, 0);
}

#define MFMA16(a, b, c) __builtin_amdgcn_mfma_f32_16x16x32_bf16((a), (b), (c), 0, 0, 0)
#define MFMA32(a, b, c) __builtin_amdgcn_mfma_f32_32x32x16_bf16((a), (b), (c), 0, 0, 0)

#define LOG2E 1.4426950408889634f

// ---------------- weight / pe cast ----------------

__global__ void k_cast_wpe(const float* __restrict__ Wq, const float* __restrict__ Wk,
                           const float* __restrict__ Wv, const float* __restrict__ Wo,
                           const float* __restrict__ pe, u16* __restrict__ wbf,
                           u16* __restrict__ pet) {
  const int bx = blockIdx.x;
  if (bx < 2048) {
    int i = bx * 256 + threadIdx.x;
    int wsel = i >> 17;
    int j = (i & 131071) * 8;
    const float* src = wsel == 0 ? Wq : wsel == 1 ? Wk : wsel == 2 ? Wv : Wo;
    float s = wsel == 0 ? 0.125f * LOG2E : 1.0f;  // fold 1/sqrt(D)*log2e into Wq
    f32x4 a = *(const f32x4*)(src + j);
    f32x4 b = *(const f32x4*)(src + j + 4);
    u16x8 o;
    o[0] = f2b(a[0] * s); o[1] = f2b(a[1] * s); o[2] = f2b(a[2] * s); o[3] = f2b(a[3] * s);
    o[4] = f2b(b[0] * s); o[5] = f2b(b[1] * s); o[6] = f2b(b[2] * s); o[7] = f2b(b[3] * s);
    *(u16x8*)(wbf + (size_t)wsel * 1048576 + j) = o;
  } else {
    int i = (bx - 2048) * 256 + threadIdx.x;  // pet[j][d] = pe[d][j]
    int j = i >> 6, d = i & 63;
    pet[i] = f2b(pe[d * 1024 + j]);
  }
}

// ---------------- fused cast+projection GEMM (r15-exact structure) ----------------
// 1792 blocks: [0,256) q, [256,1024) k, [1024,1792) v.  BK=32, single-barrier dbuf.
// Only change vs r15: seg-3 writes V^T TILED: vtb[head][t/32][d][t%32] so attn's
// V fragment loads are 64B-stride coalesced (2 lanes/line) instead of 3KB-stride gathers.

__global__ __launch_bounds__(256, 3) void k_proj(const float* __restrict__ query,
                                                 const float* __restrict__ key,
                                                 const float* __restrict__ value,
                                                 const u16* __restrict__ wbf,
                                                 u16* __restrict__ qb,
                                                 u16* __restrict__ kb,
                                                 u16* __restrict__ vtb) {
  __shared__ __align__(16) u16 As[2][128 * 40];
  __shared__ __align__(16) u16 Bs[2][128 * 32];
  const int tid = threadIdx.x;
  const int lane = tid & 63;
  const int w = tid >> 6;
  const int lr = lane & 15;
  const int lg = lane >> 4;
  const int wr = w >> 1;
  const int wc = w & 1;

  const int bx = blockIdx.x;
  int seg, lbx, segsz;
  const float* X;
  const u16* W;
  if (bx < 256)       { seg = 1; lbx = bx;        segsz = 256; X = query; W = wbf; }
  else if (bx < 1024) { seg = 2; lbx = bx - 256;  segsz = 768; X = key;   W = wbf + 1048576; }
  else                { seg = 3; lbx = bx - 1024; segsz = 768; X = value; W = wbf + 2097152; }
  const int bxs = (lbx & 7) * (segsz >> 3) + (lbx >> 3);  // segment-local XCD swizzle
  const int c0 = (bxs & 7) << 7;
  const int r0 = (bxs >> 3) << 7;

  f32x4 acc[4][4];
#pragma unroll
  for (int i = 0; i < 4; ++i)
#pragma unroll
    for (int j = 0; j < 4; ++j) acc[i][j] = (f32x4){0.f, 0.f, 0.f, 0.f};

  const int srow = lane >> 2;
  const int sch = (lane & 3) * 8;
  const float* gA = X + (size_t)(r0 + w * 32 + srow) * 1024 + sch;
  const u16* gB = W + (size_t)(c0 + w * 32 + srow) * 1024 + sch;
  const int aoff = (w * 32 + srow) * 40 + sch;   // u16 offset within As[buf]
  const int boff = w * 1024;                     // u16 offset within Bs[buf]

  // prologue: stage tile 0 into buffer 0
  {
    f32x4 a0 = *(const f32x4*)(gA);
    f32x4 a1 = *(const f32x4*)(gA + 4);
    f32x4 a2 = *(const f32x4*)(gA + 16 * 1024);
    f32x4 a3 = *(const f32x4*)(gA + 16 * 1024 + 4);
    gload16(gB, &Bs[0][boff]);
    gload16(gB + 16 * 1024, &Bs[0][boff + 16 * 32]);
    u16x8 p0, p1;
    p0[0] = f2b(a0[0]); p0[1] = f2b(a0[1]); p0[2] = f2b(a0[2]); p0[3] = f2b(a0[3]);
    p0[4] = f2b(a1[0]); p0[5] = f2b(a1[1]); p0[6] = f2b(a1[2]); p0[7] = f2b(a1[3]);
    p1[0] = f2b(a2[0]); p1[1] = f2b(a2[1]); p1[2] = f2b(a2[2]); p1[3] = f2b(a2[3]);
    p1[4] = f2b(a3[0]); p1[5] = f2b(a3[1]); p1[6] = f2b(a3[2]); p1[7] = f2b(a3[3]);
    *(u16x8*)(&As[0][aoff]) = p0;
    *(u16x8*)(&As[0][aoff + 16 * 40]) = p1;
  }

  for (int kt = 0; kt < 32; ++kt) {
    const int cur = kt & 1;
    const int nxt = cur ^ 1;
    __syncthreads();  // tile kt data (A ds_writes + B gloads from prev iter) now visible

    f32x4 n0, n1, n2, n3;
    const bool more = (kt < 31);
    if (more) {
      const int k1 = (kt + 1) * 32;
      n0 = *(const f32x4*)(gA + k1);
      n1 = *(const f32x4*)(gA + k1 + 4);
      n2 = *(const f32x4*)(gA + k1 + 16 * 1024);
      n3 = *(const f32x4*)(gA + k1 + 16 * 1024 + 4);
      gload16(gB + k1, &Bs[nxt][boff]);
      gload16(gB + k1 + 16 * 1024, &Bs[nxt][boff + 16 * 32]);
    }

    // compute tile kt from buffer cur (loads for kt+1 in flight)
    bf16x8 af[4], bfr[4];
#pragma unroll
    for (int mi = 0; mi < 4; ++mi)
      af[mi] = *(const bf16x8*)(&As[cur][(wr * 64 + mi * 16 + lr) * 40 + lg * 8]);
#pragma unroll
    for (int ci = 0; ci < 4; ++ci)
      bfr[ci] = *(const bf16x8*)(&Bs[cur][(wc * 64 + ci * 16 + lr) * 32 + lg * 8]);
#pragma unroll
    for (int mi = 0; mi < 4; ++mi)
#pragma unroll
      for (int ci = 0; ci < 4; ++ci) acc[mi][ci] = MFMA16(af[mi], bfr[ci], acc[mi][ci]);

    // write-late A staging for tile kt+1 (f32 loads have landed under compute)
    if (more) {
      u16x8 p0, p1;
      p0[0] = f2b(n0[0]); p0[1] = f2b(n0[1]); p0[2] = f2b(n0[2]); p0[3] = f2b(n0[3]);
      p0[4] = f2b(n1[0]); p0[5] = f2b(n1[1]); p0[6] = f2b(n1[2]); p0[7] = f2b(n1[3]);
      p1[0] = f2b(n2[0]); p1[1] = f2b(n2[1]); p1[2] = f2b(n2[2]); p1[3] = f2b(n2[3]);
      p1[4] = f2b(n3[0]); p1[5] = f2b(n3[1]); p1[6] = f2b(n3[2]); p1[7] = f2b(n3[3]);
      *(u16x8*)(&As[nxt][aoff]) = p0;
      *(u16x8*)(&As[nxt][aoff + 16 * 40]) = p1;
    }
  }

  const int rbase = r0 + wr * 64;
  const int cbase = c0 + wc * 64;
  if (seg == 1) {
    // q: [b*16+h][m][64]
#pragma unroll
    for (int mi = 0; mi < 4; ++mi)
#pragma unroll
      for (int ci = 0; ci < 4; ++ci) {
        const int c = cbase + ci * 16 + lr;
        const int h = c >> 6, d = c & 63;
        const int rr = rbase + mi * 16 + lg * 4;
#pragma unroll
        for (int r = 0; r < 4; ++r) {
          const int rg = rr + r;
          const int b = rg >> 9, mm = rg & 511;
          qb[((size_t)(b * 16 + h) * 512 + mm) * 64 + d] = f2b(acc[mi][ci][r]);
        }
      }
  } else if (seg == 2) {
    // k: [b*16+h][t][64]
#pragma unroll
    for (int mi = 0; mi < 4; ++mi)
#pragma unroll
      for (int ci = 0; ci < 4; ++ci) {
        const int c = cbase + ci * 16 + lr;
        const int h = c >> 6, d = c & 63;
        const int rr = rbase + mi * 16 + lg * 4;
#pragma unroll
        for (int r = 0; r < 4; ++r) {
          const int rg = rr + r;
          const int b = rg / 1536;
          const int t = rg - b * 1536;
          kb[((size_t)(b * 16 + h) * 1536 + t) * 64 + d] = f2b(acc[mi][ci][r]);
        }
      }
  } else {
    // v^T TILED: vtb[b*16+h][t/32][d][t%32]  (same quads as r15, new addresses)
#pragma unroll
    for (int mi = 0; mi < 4; ++mi)
#pragma unroll
      for (int ci = 0; ci < 4; ++ci) {
        const int c = cbase + ci * 16 + lr;
        const int h = c >> 6, d = c & 63;
        const int rr = rbase + mi * 16 + lg * 4;
        const int b = rr / 1536;
        const int t = rr - b * 1536;
        const int tt = t >> 5;   // 32-key tile index (0..47)
        const int tl = t & 31;   // 4-aligned offset within tile
        u16x4 pk;
#pragma unroll
        for (int r = 0; r < 4; ++r) pk[r] = f2b(acc[mi][ci][r]);
        *(u16x4*)(vtb + (((size_t)(b * 16 + h) * 48 + tt) * 64 + d) * 32 + tl) = pk;
      }
  }
}

// ---------------- output GEMM: d_out = ctx(bf16) * Wo^T (fp32 out) ----------------

__global__ __launch_bounds__(256, 2) void k_out(const u16* __restrict__ X,
                                                const u16* __restrict__ W,
                                                float* __restrict__ Y) {
  __shared__ __align__(16) u16 As[128 * 32];
  __shared__ __align__(16) u16 Bs[128 * 32];
  const int tid = threadIdx.x;
  const int lane = tid & 63;
  const int w = tid >> 6;
  const int lr = lane & 15;
  const int lg = lane >> 4;
  const int wr = w >> 1;
  const int wc = w & 1;
  const int bx = blockIdx.x;
  const int bxs = (bx & 7) * 32 + (bx >> 3);
  const int c0 = (bxs & 7) << 7;
  const int r0 = (bxs >> 3) << 7;

  f32x4 acc[4][4];
#pragma unroll
  for (int i = 0; i < 4; ++i)
#pragma unroll
    for (int j = 0; j < 4; ++j) acc[i][j] = (f32x4){0.f, 0.f, 0.f, 0.f};

  const int srow = lane >> 2;
  const int sch = (lane & 3) * 8;
  const u16* gA = X + (size_t)(r0 + w * 32 + srow) * 1024 + sch;
  const u16* gB = W + (size_t)(c0 + w * 32 + srow) * 1024 + sch;
  u16* lA = As + w * 32 * 32;
  u16* lB = Bs + w * 32 * 32;

  for (int kt = 0; kt < 32; ++kt) {
    const int k0 = kt * 32;
    gload16(gA + k0, lA);
    gload16(gA + k0 + 16 * 1024, lA + 16 * 32);
    gload16(gB + k0, lB);
    gload16(gB + k0 + 16 * 1024, lB + 16 * 32);
    __syncthreads();
    bf16x8 af[4], bfr[4];
#pragma unroll
    for (int mi = 0; mi < 4; ++mi)
      af[mi] = *(const bf16x8*)(As + (wr * 64 + mi * 16 + lr) * 32 + lg * 8);
#pragma unroll
    for (int ci = 0; ci < 4; ++ci)
      bfr[ci] = *(const bf16x8*)(Bs + (wc * 64 + ci * 16 + lr) * 32 + lg * 8);
#pragma unroll
    for (int mi = 0; mi < 4; ++mi)
#pragma unroll
      for (int ci = 0; ci < 4; ++ci) acc[mi][ci] = MFMA16(af[mi], bfr[ci], acc[mi][ci]);
    __syncthreads();
  }

  const int rbase = r0 + wr * 64;
  const int cbase = c0 + wc * 64;
#pragma unroll
  for (int mi = 0; mi < 4; ++mi)
#pragma unroll
    for (int ci = 0; ci < 4; ++ci) {
      const int c = cbase + ci * 16 + lr;
      const int rr = rbase + mi * 16 + lg * 4;
#pragma unroll
      for (int r = 0; r < 4; ++r) Y[(size_t)(rr + r) * 1024 + c] = acc[mi][ci][r];
    }
}

// ---------------- fused sliding-window attention (r11-exact; tiled-V loads) ----------------
// block = (head bk, 32 q-rows m0); 2048 blocks; 4 waves split the 33 t-tiles.

__global__ __launch_bounds__(256, 2) void k_attn(const u16* __restrict__ qb,
                                                 const u16* __restrict__ kb,
                                                 const u16* __restrict__ vtb,
                                                 const u16* __restrict__ pet,
                                                 u16* __restrict__ ctx) {
  __shared__ __align__(16) u16 posk[32 * 1060];  // [m][x], x = j + m (skewed)
  __shared__ __align__(16) u16 Pb[4][32 * 40];   // per-wave P staging [m][t]

  const int tid = threadIdx.x;
  const int lane = tid & 63;
  const int w = tid >> 6;
  const int ml = lane & 31;
  const int hi = lane >> 5;
  const int bx = blockIdx.x;
  const int swz = (bx & 7) * 256 + (bx >> 3);  // bijective XCD swizzle
  const int bk = swz >> 4;
  const int m0 = (swz & 15) << 5;

  const u16* Qh = qb + (size_t)bk * (512 * 64);
  const u16* Kh = kb + (size_t)bk * (1536 * 64);
  const u16* Vh = vtb + (size_t)bk * (48 * 64 * 32);  // tiled: [tt][d][tl]

  // Q fragments (B-operand: col=m=ml, k = ks*16 + hi*8 + i)
  bf16x8 qf[4];
#pragma unroll
  for (int ks = 0; ks < 4; ++ks)
    qf[ks] = *(const bf16x8*)(Qh + (m0 + ml) * 64 + ks * 16 + hi * 8);

  // pos prologue: pos[m][j] = q_m . pe_j via MFMA32; skew-store x = j + m
  for (int jt = 0; jt < 8; ++jt) {
    const int j0 = w * 256 + jt * 32;
    f32x16 c = zero16();
#pragma unroll
    for (int ks = 0; ks < 4; ++ks) {
      bf16x8 a = *(const bf16x8*)(pet + (j0 + ml) * 64 + ks * 16 + hi * 8);
      c = MFMA32(a, qf[ks], c);
    }
#pragma unroll
    for (int r = 0; r < 16; ++r) {
      const int tl = (r & 3) + 8 * (r >> 2) + 4 * hi;  // j_local
      posk[ml * 1060 + j0 + tl + ml] = f2b_fast(c[r]); // x = j + m
    }
  }
  __syncthreads();

  float mrun = -1e30f, lrun = 0.f;
  f32x16 oA = zero16(), oB = zero16();  // d 0..31 / 32..63

  auto loadKV = [&](bf16x8(&kf)[4], bf16x8(&vf)[2][2], int s) {
    const int t0 = m0 + s * 32;
#pragma unroll
    for (int ks = 0; ks < 4; ++ks)
      kf[ks] = *(const bf16x8*)(Kh + (t0 + ml) * 64 + ks * 16 + hi * 8);
    const int tt = (m0 >> 5) + s;  // tiled-V: coalesced 64B-stride lane access
#pragma unroll
    for (int dt = 0; dt < 2; ++dt)
#pragma unroll
      for (int kt = 0; kt < 2; ++kt)
        vf[dt][kt] = *(const bf16x8*)(Vh + ((size_t)tt * 64 + dt * 32 + ml) * 32 + kt * 16 + hi * 8);
  };

  auto doTile = [&](int s, bf16x8(&kf)[4], bf16x8(&vf)[2][2]) {
    // QK': C'[t][m], col m=ml, rows t=(r&3)+8*(r>>2)+4*hi
    __builtin_amdgcn_s_setprio(1);
    f32x16 sc = zero16();
#pragma unroll
    for (int ks = 0; ks < 4; ++ks) sc = MFMA32(kf[ks], qf[ks], sc);
    __builtin_amdgcn_s_setprio(0);

    // pos add at x = s*32 + tl (skew cancels m); explicit edge mask on s in {0,32}
    const bool edge = (s == 0) | (s == 32);
#pragma unroll
    for (int q = 0; q < 4; ++q) {
      const u16x4 pk = *(const u16x4*)(posk + ml * 1060 + s * 32 + q * 8 + hi * 4);
#pragma unroll
      for (int r0 = 0; r0 < 4; ++r0) {
        const int r = q * 4 + r0;
        float v = sc[r] + b2f(pk[r0]);
        if (edge) {
          const int j = s * 32 + q * 8 + hi * 4 + r0 - ml;
          v = (j >= 0 && j < 1024) ? v : -1e30f;
        }
        sc[r] = v;
      }
    }

    // row max: in-lane tree + shfl_xor(32)
    float a0 = fmaxf(fmaxf(sc[0], sc[1]), fmaxf(sc[2], sc[3]));
    float a1 = fmaxf(fmaxf(sc[4], sc[5]), fmaxf(sc[6], sc[7]));
    float a2 = fmaxf(fmaxf(sc[8], sc[9]), fmaxf(sc[10], sc[11]));
    float a3 = fmaxf(fmaxf(sc[12], sc[13]), fmaxf(sc[14], sc[15]));
    float pmax = fmaxf(fmaxf(a0, a1), fmaxf(a2, a3));
    pmax = fmaxf(pmax, __shfl_xor(pmax, 32));

    // exact deferred rescale: when no column max grew, scale == 1.0 -> skip
    if (__ballot(pmax > mrun)) {
      const float mn = fmaxf(mrun, pmax);
      const float scale = __builtin_amdgcn_exp2f(mrun - mn);
      lrun *= scale;
      mrun = mn;
#pragma unroll
      for (int r = 0; r < 16; ++r) { oA[r] *= scale; oB[r] *= scale; }
    }

#pragma unroll
    for (int r = 0; r < 16; ++r) sc[r] = __builtin_amdgcn_exp2f(sc[r] - mrun);
    float s0 = (sc[0] + sc[1]) + (sc[2] + sc[3]);
    float s1 = (sc[4] + sc[5]) + (sc[6] + sc[7]);
    float s2 = (sc[8] + sc[9]) + (sc[10] + sc[11]);
    float s3 = (sc[12] + sc[13]) + (sc[14] + sc[15]);
    float rs = (s0 + s1) + (s2 + s3);
    rs += __shfl_xor(rs, 32);
    lrun += rs;

    // P staging via LDS (u16-family stores + fence — HW-validated path)
#pragma unroll
    for (int q = 0; q < 4; ++q) {
      u16x4 pk;
#pragma unroll
      for (int r0 = 0; r0 < 4; ++r0) pk[r0] = f2b_fast(sc[q * 4 + r0]);
      *(u16x4*)(&Pb[w][ml * 40 + q * 8 + hi * 4]) = pk;
    }
    asm volatile("" ::: "memory");
    bf16x8 pb0 = *(const bf16x8*)(&Pb[w][ml * 40 + hi * 8]);
    bf16x8 pb1 = *(const bf16x8*)(&Pb[w][ml * 40 + 16 + hi * 8]);

    __builtin_amdgcn_s_setprio(1);
    oA = MFMA32(vf[0][0], pb0, oA);
    oB = MFMA32(vf[1][0], pb0, oB);
    oA = MFMA32(vf[0][1], pb1, oA);
    oB = MFMA32(vf[1][1], pb1, oB);
    __builtin_amdgcn_s_setprio(0);
  };

  // main loop: wave w owns tiles s = w, w+4, ..., <=32; K/V double-buffered
  bf16x8 kfA[4], kfB[4], vfA[2][2], vfB[2][2];
  loadKV(kfA, vfA, w);
  for (int s = w;;) {
    const int sn = s + 4;
    if (sn <= 32) loadKV(kfB, vfB, sn);
    doTile(s, kfA, vfA);
    if (sn > 32) break;
    s = sn;
    const int sn2 = s + 4;
    if (sn2 <= 32) loadKV(kfA, vfA, sn2);
    doTile(s, kfB, vfB);
    if (sn2 > 32) break;
    s = sn2;
  }

  // merge the 4 wave-partials (scratch overlays posk; stride 68 avoids conflicts)
  __syncthreads();
  float* mO = (float*)posk;         // [4][32][68]
  float* mM = mO + 4 * 32 * 68;     // [4][32]
  float* mL = mM + 128;             // [4][32]
#pragma unroll
  for (int q = 0; q < 4; ++q) {
    *(f32x4*)(mO + (w * 32 + ml) * 68 + q * 8 + hi * 4) =
        (f32x4){oA[4 * q], oA[4 * q + 1], oA[4 * q + 2], oA[4 * q + 3]};
    *(f32x4*)(mO + (w * 32 + ml) * 68 + 32 + q * 8 + hi * 4) =
        (f32x4){oB[4 * q], oB[4 * q + 1], oB[4 * q + 2], oB[4 * q + 3]};
  }
  if (hi == 0) {
    mM[w * 32 + ml] = mrun;
    mL[w * 32 + ml] = lrun;
  }
  __syncthreads();

  const int m = tid >> 3;
  const int d0 = (tid & 7) * 8;
  float mw4[4], lw4[4], M = -3e38f;
#pragma unroll
  for (int i = 0; i < 4; ++i) {
    mw4[i] = mM[i * 32 + m];
    lw4[i] = mL[i * 32 + m];
    M = fmaxf(M, mw4[i]);
  }
  float den = 0.f;
  float o[8] = {0.f, 0.f, 0.f, 0.f, 0.f, 0.f, 0.f, 0.f};
#pragma unroll
  for (int i = 0; i < 4; ++i) {
    const float e = __builtin_amdgcn_exp2f(mw4[i] - M);
    den += lw4[i] * e;
    f32x4 a = *(const f32x4*)(mO + (i * 32 + m) * 68 + d0);
    f32x4 b = *(const f32x4*)(mO + (i * 32 + m) * 68 + d0 + 4);
#pragma unroll
    for (int r = 0; r < 4; ++r) {
      o[r] += e * a[r];
      o[4 + r] += e * b[r];
    }
  }
  const float inv = 1.f / den;
  u16x8 ov;
#pragma unroll
  for (int i = 0; i < 8; ++i) ov[i] = f2b_fast(o[i] * inv);
  const int b_ = bk >> 4, h = bk & 15;
  *(u16x8*)(ctx + ((size_t)(b_ * 512 + m0 + m)) * 1024 + h * 64 + d0) = ov;
}

// ---------------- launch ----------------

extern "C" void kernel_launch(void* const* d_in, const int* in_sizes, int n_in,
                              void* d_out, int out_size, void* d_ws, size_t ws_size,
                              hipStream_t stream) {
  (void)in_sizes; (void)n_in; (void)out_size; (void)ws_size;
  const float* query = (const float*)d_in[0];
  const float* key   = (const float*)d_in[1];
  const float* value = (const float*)d_in[2];
  const float* pe    = (const float*)d_in[3];
  const float* Wq    = (const float*)d_in[4];
  const float* Wk    = (const float*)d_in[5];
  const float* Wv    = (const float*)d_in[6];
  const float* Wo    = (const float*)d_in[7];

  u16* wbf = (u16*)d_ws;             // 4 x 1M
  u16* pet = wbf + 4194304;          // 65536
  u16* qb  = pet + 65536;            // 4194304
  u16* kb  = qb + 4194304;           // 12582912
  u16* vtb = kb + 12582912;          // 12582912 (tiled: 128 x 48 x 64 x 32)
  u16* ctx = vtb + 12582912;         // 4194304

  k_cast_wpe<<<2304, 256, 0, stream>>>(Wq, Wk, Wv, Wo, pe, wbf, pet);
  k_proj<<<1792, 256, 0, stream>>>(query, key, value, wbf, qb, kb, vtb);
  k_attn<<<2048, 256, 0, stream>>>(qb, kb, vtb, pet, ctx);
  k_out<<<256, 256, 0, stream>>>(ctx, wbf + 3145728, (float*)d_out);
}

// Round 18
// 192.579 us; speedup vs baseline: 1.3793x; 1.0844x over previous
//
#include <hip/hip_runtime.h>

using u16 = unsigned short;
using u32 = unsigned int;

typedef short bf16x8 __attribute__((ext_vector_type(8)));
typedef float f32x4 __attribute__((ext_vector_type(4)));
typedef float f32x16 __attribute__((ext_vector_type(16)));
typedef u16 u16x4 __attribute__((ext_vector_type(4)));
typedef u16 u16x8 __attribute__((ext_vector_type(8)));

__device__ __forceinline__ u16 f2b(float f) {  // RNE
  u32 u = __builtin_bit_cast(u32, f);
  u += 0x7fffu + ((u >> 16) & 1u);
  return (u16)(u >> 16);
}
__device__ __forceinline__ u16 f2b_fast(float f) {  // round-half-up: 2 VALU
  u32 u = __builtin_bit_cast(u32, f);
  return (u16)((u + 0x8000u) >> 16);
}
__device__ __forceinline__ float b2f(u16 h) {
  u32 u = ((u32)h) << 16;
  return __builtin_bit_cast(float, u);
}
__device__ __forceinline__ f32x16 zero16() {
  f32x16 v;
#pragma unroll
  for (int i = 0; i < 16; ++i) v[i] = 0.f;
  return v;
}

typedef __attribute__((address_space(1))) const u16 gas_u16;
typedef __attribute__((address_space(3))) u16 las_u16;

__device__ __forceinline__ void gload16(const u16* g, u16* l) {
  __builtin_amdgcn_global_load_lds((const gas_u16*)g, (las_u16*)l, 16, 0, 0);
}

#define MFMA16(a, b, c) __builtin_amdgcn_mfma_f32_16x16x32_bf16((a), (b), (c), 0, 0, 0)
#define MFMA32(a, b, c) __builtin_amdgcn_mfma_f32_32x32x16_bf16((a), (b), (c), 0, 0, 0)

#define LOG2E 1.4426950408889634f

// ---------------- weight / pe cast ----------------
// pet TILED: pet[j/32][d/8][j%32][8]  (coalesced attn prologue loads)

__global__ void k_cast_wpe(const float* __restrict__ Wq, const float* __restrict__ Wk,
                           const float* __restrict__ Wv, const float* __restrict__ Wo,
                           const float* __restrict__ pe, u16* __restrict__ wbf,
                           u16* __restrict__ pet) {
  const int bx = blockIdx.x;
  if (bx < 2048) {
    int i = bx * 256 + threadIdx.x;
    int wsel = i >> 17;
    int j = (i & 131071) * 8;
    const float* src = wsel == 0 ? Wq : wsel == 1 ? Wk : wsel == 2 ? Wv : Wo;
    float s = wsel == 0 ? 0.125f * LOG2E : 1.0f;  // fold 1/sqrt(D)*log2e into Wq
    f32x4 a = *(const f32x4*)(src + j);
    f32x4 b = *(const f32x4*)(src + j + 4);
    u16x8 o;
    o[0] = f2b(a[0] * s); o[1] = f2b(a[1] * s); o[2] = f2b(a[2] * s); o[3] = f2b(a[3] * s);
    o[4] = f2b(b[0] * s); o[5] = f2b(b[1] * s); o[6] = f2b(b[2] * s); o[7] = f2b(b[3] * s);
    *(u16x8*)(wbf + (size_t)wsel * 1048576 + j) = o;
  } else {
    int i = (bx - 2048) * 256 + threadIdx.x;  // j = i>>6, d = i&63
    int j = i >> 6, d = i & 63;
    pet[(((j >> 5) * 8 + (d >> 3)) * 32 + (j & 31)) * 8 + (d & 7)] = f2b(pe[d * 1024 + j]);
  }
}

// ---------------- fused cast+projection GEMM (r15-exact structure) ----------------
// 1792 blocks: [0,256) q, [256,1024) k, [1024,1792) v.  BK=32, single-barrier dbuf.
// Epilogues write TILED head layouts: qb[h][m/32][d/8][m%32][8], kb[h][t/32][d/8][t%32][8],
// vtb[h][t/32][d][t%32] — so every attn fragment load is 16B/lane coalesced.

__global__ __launch_bounds__(256, 3) void k_proj(const float* __restrict__ query,
                                                 const float* __restrict__ key,
                                                 const float* __restrict__ value,
                                                 const u16* __restrict__ wbf,
                                                 u16* __restrict__ qb,
                                                 u16* __restrict__ kb,
                                                 u16* __restrict__ vtb) {
  __shared__ __align__(16) u16 As[2][128 * 40];
  __shared__ __align__(16) u16 Bs[2][128 * 32];
  const int tid = threadIdx.x;
  const int lane = tid & 63;
  const int w = tid >> 6;
  const int lr = lane & 15;
  const int lg = lane >> 4;
  const int wr = w >> 1;
  const int wc = w & 1;

  const int bx = blockIdx.x;
  int seg, lbx, segsz;
  const float* X;
  const u16* W;
  if (bx < 256)       { seg = 1; lbx = bx;        segsz = 256; X = query; W = wbf; }
  else if (bx < 1024) { seg = 2; lbx = bx - 256;  segsz = 768; X = key;   W = wbf + 1048576; }
  else                { seg = 3; lbx = bx - 1024; segsz = 768; X = value; W = wbf + 2097152; }
  const int bxs = (lbx & 7) * (segsz >> 3) + (lbx >> 3);  // segment-local XCD swizzle
  const int c0 = (bxs & 7) << 7;
  const int r0 = (bxs >> 3) << 7;

  f32x4 acc[4][4];
#pragma unroll
  for (int i = 0; i < 4; ++i)
#pragma unroll
    for (int j = 0; j < 4; ++j) acc[i][j] = (f32x4){0.f, 0.f, 0.f, 0.f};

  const int srow = lane >> 2;
  const int sch = (lane & 3) * 8;
  const float* gA = X + (size_t)(r0 + w * 32 + srow) * 1024 + sch;
  const u16* gB = W + (size_t)(c0 + w * 32 + srow) * 1024 + sch;
  const int aoff = (w * 32 + srow) * 40 + sch;   // u16 offset within As[buf]
  const int boff = w * 1024;                     // u16 offset within Bs[buf]

  // prologue: stage tile 0 into buffer 0
  {
    f32x4 a0 = *(const f32x4*)(gA);
    f32x4 a1 = *(const f32x4*)(gA + 4);
    f32x4 a2 = *(const f32x4*)(gA + 16 * 1024);
    f32x4 a3 = *(const f32x4*)(gA + 16 * 1024 + 4);
    gload16(gB, &Bs[0][boff]);
    gload16(gB + 16 * 1024, &Bs[0][boff + 16 * 32]);
    u16x8 p0, p1;
    p0[0] = f2b(a0[0]); p0[1] = f2b(a0[1]); p0[2] = f2b(a0[2]); p0[3] = f2b(a0[3]);
    p0[4] = f2b(a1[0]); p0[5] = f2b(a1[1]); p0[6] = f2b(a1[2]); p0[7] = f2b(a1[3]);
    p1[0] = f2b(a2[0]); p1[1] = f2b(a2[1]); p1[2] = f2b(a2[2]); p1[3] = f2b(a2[3]);
    p1[4] = f2b(a3[0]); p1[5] = f2b(a3[1]); p1[6] = f2b(a3[2]); p1[7] = f2b(a3[3]);
    *(u16x8*)(&As[0][aoff]) = p0;
    *(u16x8*)(&As[0][aoff + 16 * 40]) = p1;
  }

  for (int kt = 0; kt < 32; ++kt) {
    const int cur = kt & 1;
    const int nxt = cur ^ 1;
    __syncthreads();  // tile kt data (A ds_writes + B gloads from prev iter) now visible

    f32x4 n0, n1, n2, n3;
    const bool more = (kt < 31);
    if (more) {
      const int k1 = (kt + 1) * 32;
      n0 = *(const f32x4*)(gA + k1);
      n1 = *(const f32x4*)(gA + k1 + 4);
      n2 = *(const f32x4*)(gA + k1 + 16 * 1024);
      n3 = *(const f32x4*)(gA + k1 + 16 * 1024 + 4);
      gload16(gB + k1, &Bs[nxt][boff]);
      gload16(gB + k1 + 16 * 1024, &Bs[nxt][boff + 16 * 32]);
    }

    // compute tile kt from buffer cur (loads for kt+1 in flight)
    bf16x8 af[4], bfr[4];
#pragma unroll
    for (int mi = 0; mi < 4; ++mi)
      af[mi] = *(const bf16x8*)(&As[cur][(wr * 64 + mi * 16 + lr) * 40 + lg * 8]);
#pragma unroll
    for (int ci = 0; ci < 4; ++ci)
      bfr[ci] = *(const bf16x8*)(&Bs[cur][(wc * 64 + ci * 16 + lr) * 32 + lg * 8]);
#pragma unroll
    for (int mi = 0; mi < 4; ++mi)
#pragma unroll
      for (int ci = 0; ci < 4; ++ci) acc[mi][ci] = MFMA16(af[mi], bfr[ci], acc[mi][ci]);

    // write-late A staging for tile kt+1 (f32 loads have landed under compute)
    if (more) {
      u16x8 p0, p1;
      p0[0] = f2b(n0[0]); p0[1] = f2b(n0[1]); p0[2] = f2b(n0[2]); p0[3] = f2b(n0[3]);
      p0[4] = f2b(n1[0]); p0[5] = f2b(n1[1]); p0[6] = f2b(n1[2]); p0[7] = f2b(n1[3]);
      p1[0] = f2b(n2[0]); p1[1] = f2b(n2[1]); p1[2] = f2b(n2[2]); p1[3] = f2b(n2[3]);
      p1[4] = f2b(n3[0]); p1[5] = f2b(n3[1]); p1[6] = f2b(n3[2]); p1[7] = f2b(n3[3]);
      *(u16x8*)(&As[nxt][aoff]) = p0;
      *(u16x8*)(&As[nxt][aoff + 16 * 40]) = p1;
    }
  }

  const int rbase = r0 + wr * 64;
  const int cbase = c0 + wc * 64;
  if (seg == 1) {
    // q TILED: qb[b*16+h][m/32][d/8][m%32][8]
#pragma unroll
    for (int mi = 0; mi < 4; ++mi)
#pragma unroll
      for (int ci = 0; ci < 4; ++ci) {
        const int c = cbase + ci * 16 + lr;
        const int h = c >> 6, d = c & 63;
        const int rr = rbase + mi * 16 + lg * 4;
#pragma unroll
        for (int r = 0; r < 4; ++r) {
          const int rg = rr + r;
          const int b = rg >> 9, mm = rg & 511;
          qb[((((size_t)(b * 16 + h) * 16 + (mm >> 5)) * 8 + (d >> 3)) * 32 + (mm & 31)) * 8 + (d & 7)] =
              f2b(acc[mi][ci][r]);
        }
      }
  } else if (seg == 2) {
    // k TILED: kb[b*16+h][t/32][d/8][t%32][8]
#pragma unroll
    for (int mi = 0; mi < 4; ++mi)
#pragma unroll
      for (int ci = 0; ci < 4; ++ci) {
        const int c = cbase + ci * 16 + lr;
        const int h = c >> 6, d = c & 63;
        const int rr = rbase + mi * 16 + lg * 4;
#pragma unroll
        for (int r = 0; r < 4; ++r) {
          const int rg = rr + r;
          const int b = rg / 1536;
          const int t = rg - b * 1536;
          kb[((((size_t)(b * 16 + h) * 48 + (t >> 5)) * 8 + (d >> 3)) * 32 + (t & 31)) * 8 + (d & 7)] =
              f2b(acc[mi][ci][r]);
        }
      }
  } else {
    // v^T TILED: vtb[b*16+h][t/32][d][t%32]
#pragma unroll
    for (int mi = 0; mi < 4; ++mi)
#pragma unroll
      for (int ci = 0; ci < 4; ++ci) {
        const int c = cbase + ci * 16 + lr;
        const int h = c >> 6, d = c & 63;
        const int rr = rbase + mi * 16 + lg * 4;
        const int b = rr / 1536;
        const int t = rr - b * 1536;
        const int tt = t >> 5;
        const int tl = t & 31;
        u16x4 pk;
#pragma unroll
        for (int r = 0; r < 4; ++r) pk[r] = f2b(acc[mi][ci][r]);
        *(u16x4*)(vtb + (((size_t)(b * 16 + h) * 48 + tt) * 64 + d) * 32 + tl) = pk;
      }
  }
}

// ---------------- output GEMM: d_out = ctx(bf16) * Wo^T (fp32 out) ----------------

__global__ __launch_bounds__(256, 2) void k_out(const u16* __restrict__ X,
                                                const u16* __restrict__ W,
                                                float* __restrict__ Y) {
  __shared__ __align__(16) u16 As[128 * 32];
  __shared__ __align__(16) u16 Bs[128 * 32];
  const int tid = threadIdx.x;
  const int lane = tid & 63;
  const int w = tid >> 6;
  const int lr = lane & 15;
  const int lg = lane >> 4;
  const int wr = w >> 1;
  const int wc = w & 1;
  const int bx = blockIdx.x;
  const int bxs = (bx & 7) * 32 + (bx >> 3);
  const int c0 = (bxs & 7) << 7;
  const int r0 = (bxs >> 3) << 7;

  f32x4 acc[4][4];
#pragma unroll
  for (int i = 0; i < 4; ++i)
#pragma unroll
    for (int j = 0; j < 4; ++j) acc[i][j] = (f32x4){0.f, 0.f, 0.f, 0.f};

  const int srow = lane >> 2;
  const int sch = (lane & 3) * 8;
  const u16* gA = X + (size_t)(r0 + w * 32 + srow) * 1024 + sch;
  const u16* gB = W + (size_t)(c0 + w * 32 + srow) * 1024 + sch;
  u16* lA = As + w * 32 * 32;
  u16* lB = Bs + w * 32 * 32;

  for (int kt = 0; kt < 32; ++kt) {
    const int k0 = kt * 32;
    gload16(gA + k0, lA);
    gload16(gA + k0 + 16 * 1024, lA + 16 * 32);
    gload16(gB + k0, lB);
    gload16(gB + k0 + 16 * 1024, lB + 16 * 32);
    __syncthreads();
    bf16x8 af[4], bfr[4];
#pragma unroll
    for (int mi = 0; mi < 4; ++mi)
      af[mi] = *(const bf16x8*)(As + (wr * 64 + mi * 16 + lr) * 32 + lg * 8);
#pragma unroll
    for (int ci = 0; ci < 4; ++ci)
      bfr[ci] = *(const bf16x8*)(Bs + (wc * 64 + ci * 16 + lr) * 32 + lg * 8);
#pragma unroll
    for (int mi = 0; mi < 4; ++mi)
#pragma unroll
      for (int ci = 0; ci < 4; ++ci) acc[mi][ci] = MFMA16(af[mi], bfr[ci], acc[mi][ci]);
    __syncthreads();
  }

  const int rbase = r0 + wr * 64;
  const int cbase = c0 + wc * 64;
#pragma unroll
  for (int mi = 0; mi < 4; ++mi)
#pragma unroll
    for (int ci = 0; ci < 4; ++ci) {
      const int c = cbase + ci * 16 + lr;
      const int rr = rbase + mi * 16 + lg * 4;
#pragma unroll
      for (int r = 0; r < 4; ++r) Y[(size_t)(rr + r) * 1024 + c] = acc[mi][ci][r];
    }
}

// ---------------- fused sliding-window attention (r17-exact logic; tiled Q/K/V/pe loads) ----------------
// block = (head bk, 32 q-rows m0); 2048 blocks; 4 waves split the 33 t-tiles.

__global__ __launch_bounds__(256, 2) void k_attn(const u16* __restrict__ qb,
                                                 const u16* __restrict__ kb,
                                                 const u16* __restrict__ vtb,
                                                 const u16* __restrict__ pet,
                                                 u16* __restrict__ ctx) {
  __shared__ __align__(16) u16 posk[32 * 1060];  // [m][x], x = j + m (skewed)
  __shared__ __align__(16) u16 Pb[4][32 * 40];   // per-wave P staging [m][t]

  const int tid = threadIdx.x;
  const int lane = tid & 63;
  const int w = tid >> 6;
  const int ml = lane & 31;
  const int hi = lane >> 5;
  const int bx = blockIdx.x;
  const int swz = (bx & 7) * 256 + (bx >> 3);  // bijective XCD swizzle
  const int bk = swz >> 4;
  const int m0 = (swz & 15) << 5;

  const u16* Qh = qb + (size_t)bk * (16 * 8 * 32 * 8);    // [mt][c][ml][8]
  const u16* Kh = kb + (size_t)bk * (48 * 8 * 32 * 8);    // [tt][c][ml][8]
  const u16* Vh = vtb + (size_t)bk * (48 * 64 * 32);      // [tt][d][tl]

  // Q fragments: tiled load, 16B/lane coalesced
  bf16x8 qf[4];
  {
    const int mt = m0 >> 5;
#pragma unroll
    for (int ks = 0; ks < 4; ++ks)
      qf[ks] = *(const bf16x8*)(Qh + (((size_t)mt * 8 + ks * 2 + hi) * 32 + ml) * 8);
  }

  // pos prologue: pos[m][j] = q_m . pe_j via MFMA32; skew-store x = j + m
  for (int jt = 0; jt < 8; ++jt) {
    const int jt8 = (w * 8 + jt) * 8;  // (j0>>5)*8, j0 = w*256 + jt*32
    f32x16 c = zero16();
#pragma unroll
    for (int ks = 0; ks < 4; ++ks) {
      bf16x8 a = *(const bf16x8*)(pet + (((size_t)(jt8 + ks * 2 + hi)) * 32 + ml) * 8);
      c = MFMA32(a, qf[ks], c);
    }
    const int j0 = w * 256 + jt * 32;
#pragma unroll
    for (int r = 0; r < 16; ++r) {
      const int tl = (r & 3) + 8 * (r >> 2) + 4 * hi;  // j_local
      posk[ml * 1060 + j0 + tl + ml] = f2b_fast(c[r]); // x = j + m
    }
  }
  __syncthreads();

  float mrun = -1e30f, lrun = 0.f;
  f32x16 oA = zero16(), oB = zero16();  // d 0..31 / 32..63

  auto loadKV = [&](bf16x8(&kf)[4], bf16x8(&vf)[2][2], int s) {
    const int tt = (m0 >> 5) + s;
#pragma unroll
    for (int ks = 0; ks < 4; ++ks)
      kf[ks] = *(const bf16x8*)(Kh + (((size_t)tt * 8 + ks * 2 + hi) * 32 + ml) * 8);
#pragma unroll
    for (int dt = 0; dt < 2; ++dt)
#pragma unroll
      for (int kt = 0; kt < 2; ++kt)
        vf[dt][kt] = *(const bf16x8*)(Vh + ((size_t)tt * 64 + dt * 32 + ml) * 32 + kt * 16 + hi * 8);
  };

  auto doTile = [&](int s, bf16x8(&kf)[4], bf16x8(&vf)[2][2]) {
    // QK': C'[t][m], col m=ml, rows t=(r&3)+8*(r>>2)+4*hi
    __builtin_amdgcn_s_setprio(1);
    f32x16 sc = zero16();
#pragma unroll
    for (int ks = 0; ks < 4; ++ks) sc = MFMA32(kf[ks], qf[ks], sc);
    __builtin_amdgcn_s_setprio(0);

    // pos add at x = s*32 + tl (skew cancels m); explicit edge mask on s in {0,32}
    const bool edge = (s == 0) | (s == 32);
#pragma unroll
    for (int q = 0; q < 4; ++q) {
      const u16x4 pk = *(const u16x4*)(posk + ml * 1060 + s * 32 + q * 8 + hi * 4);
#pragma unroll
      for (int r0 = 0; r0 < 4; ++r0) {
        const int r = q * 4 + r0;
        float v = sc[r] + b2f(pk[r0]);
        if (edge) {
          const int j = s * 32 + q * 8 + hi * 4 + r0 - ml;
          v = (j >= 0 && j < 1024) ? v : -1e30f;
        }
        sc[r] = v;
      }
    }

    // row max: in-lane tree + shfl_xor(32)
    float a0 = fmaxf(fmaxf(sc[0], sc[1]), fmaxf(sc[2], sc[3]));
    float a1 = fmaxf(fmaxf(sc[4], sc[5]), fmaxf(sc[6], sc[7]));
    float a2 = fmaxf(fmaxf(sc[8], sc[9]), fmaxf(sc[10], sc[11]));
    float a3 = fmaxf(fmaxf(sc[12], sc[13]), fmaxf(sc[14], sc[15]));
    float pmax = fmaxf(fmaxf(a0, a1), fmaxf(a2, a3));
    pmax = fmaxf(pmax, __shfl_xor(pmax, 32));

    // exact deferred rescale: when no column max grew, scale == 1.0 -> skip
    if (__ballot(pmax > mrun)) {
      const float mn = fmaxf(mrun, pmax);
      const float scale = __builtin_amdgcn_exp2f(mrun - mn);
      lrun *= scale;
      mrun = mn;
#pragma unroll
      for (int r = 0; r < 16; ++r) { oA[r] *= scale; oB[r] *= scale; }
    }

#pragma unroll
    for (int r = 0; r < 16; ++r) sc[r] = __builtin_amdgcn_exp2f(sc[r] - mrun);
    float s0 = (sc[0] + sc[1]) + (sc[2] + sc[3]);
    float s1 = (sc[4] + sc[5]) + (sc[6] + sc[7]);
    float s2 = (sc[8] + sc[9]) + (sc[10] + sc[11]);
    float s3 = (sc[12] + sc[13]) + (sc[14] + sc[15]);
    float rs = (s0 + s1) + (s2 + s3);
    rs += __shfl_xor(rs, 32);
    lrun += rs;

    // P staging via LDS (u16-family stores + fence — HW-validated path)
#pragma unroll
    for (int q = 0; q < 4; ++q) {
      u16x4 pk;
#pragma unroll
      for (int r0 = 0; r0 < 4; ++r0) pk[r0] = f2b_fast(sc[q * 4 + r0]);
      *(u16x4*)(&Pb[w][ml * 40 + q * 8 + hi * 4]) = pk;
    }
    asm volatile("" ::: "memory");
    bf16x8 pb0 = *(const bf16x8*)(&Pb[w][ml * 40 + hi * 8]);
    bf16x8 pb1 = *(const bf16x8*)(&Pb[w][ml * 40 + 16 + hi * 8]);

    __builtin_amdgcn_s_setprio(1);
    oA = MFMA32(vf[0][0], pb0, oA);
    oB = MFMA32(vf[1][0], pb0, oB);
    oA = MFMA32(vf[0][1], pb1, oA);
    oB = MFMA32(vf[1][1], pb1, oB);
    __builtin_amdgcn_s_setprio(0);
  };

  // main loop: wave w owns tiles s = w, w+4, ..., <=32; K/V double-buffered
  bf16x8 kfA[4], kfB[4], vfA[2][2], vfB[2][2];
  loadKV(kfA, vfA, w);
  for (int s = w;;) {
    const int sn = s + 4;
    if (sn <= 32) loadKV(kfB, vfB, sn);
    doTile(s, kfA, vfA);
    if (sn > 32) break;
    s = sn;
    const int sn2 = s + 4;
    if (sn2 <= 32) loadKV(kfA, vfA, sn2);
    doTile(s, kfB, vfB);
    if (sn2 > 32) break;
    s = sn2;
  }

  // merge the 4 wave-partials (scratch overlays posk; stride 68 avoids conflicts)
  __syncthreads();
  float* mO = (float*)posk;         // [4][32][68]
  float* mM = mO + 4 * 32 * 68;     // [4][32]
  float* mL = mM + 128;             // [4][32]
#pragma unroll
  for (int q = 0; q < 4; ++q) {
    *(f32x4*)(mO + (w * 32 + ml) * 68 + q * 8 + hi * 4) =
        (f32x4){oA[4 * q], oA[4 * q + 1], oA[4 * q + 2], oA[4 * q + 3]};
    *(f32x4*)(mO + (w * 32 + ml) * 68 + 32 + q * 8 + hi * 4) =
        (f32x4){oB[4 * q], oB[4 * q + 1], oB[4 * q + 2], oB[4 * q + 3]};
  }
  if (hi == 0) {
    mM[w * 32 + ml] = mrun;
    mL[w * 32 + ml] = lrun;
  }
  __syncthreads();

  const int m = tid >> 3;
  const int d0 = (tid & 7) * 8;
  float mw4[4], lw4[4], M = -3e38f;
#pragma unroll
  for (int i = 0; i < 4; ++i) {
    mw4[i] = mM[i * 32 + m];
    lw4[i] = mL[i * 32 + m];
    M = fmaxf(M, mw4[i]);
  }
  float den = 0.f;
  float o[8] = {0.f, 0.f, 0.f, 0.f, 0.f, 0.f, 0.f, 0.f};
#pragma unroll
  for (int i = 0; i < 4; ++i) {
    const float e = __builtin_amdgcn_exp2f(mw4[i] - M);
    den += lw4[i] * e;
    f32x4 a = *(const f32x4*)(mO + (i * 32 + m) * 68 + d0);
    f32x4 b = *(const f32x4*)(mO + (i * 32 + m) * 68 + d0 + 4);
#pragma unroll
    for (int r = 0; r < 4; ++r) {
      o[r] += e * a[r];
      o[4 + r] += e * b[r];
    }
  }
  const float inv = 1.f / den;
  u16x8 ov;
#pragma unroll
  for (int i = 0; i < 8; ++i) ov[i] = f2b_fast(o[i] * inv);
  const int b_ = bk >> 4, h = bk & 15;
  *(u16x8*)(ctx + ((size_t)(b_ * 512 + m0 + m)) * 1024 + h * 64 + d0) = ov;
}

// ---------------- launch ----------------

extern "C" void kernel_launch(void* const* d_in, const int* in_sizes, int n_in,
                              void* d_out, int out_size, void* d_ws, size_t ws_size,
                              hipStream_t stream) {
  (void)in_sizes; (void)n_in; (void)out_size; (void)ws_size;
  const float* query = (const float*)d_in[0];
  const float* key   = (const float*)d_in[1];
  const float* value = (const float*)d_in[2];
  const float* pe    = (const float*)d_in[3];
  const float* Wq    = (const float*)d_in[4];
  const float* Wk    = (const float*)d_in[5];
  const float* Wv    = (const float*)d_in[6];
  const float* Wo    = (const float*)d_in[7];

  u16* wbf = (u16*)d_ws;             // 4 x 1M
  u16* pet = wbf + 4194304;          // 65536 (tiled)
  u16* qb  = pet + 65536;            // 4194304 (tiled)
  u16* kb  = qb + 4194304;           // 12582912 (tiled)
  u16* vtb = kb + 12582912;          // 12582912 (tiled)
  u16* ctx = vtb + 12582912;         // 4194304

  k_cast_wpe<<<2304, 256, 0, stream>>>(Wq, Wk, Wv, Wo, pe, wbf, pet);
  k_proj<<<1792, 256, 0, stream>>>(query, key, value, wbf, qb, kb, vtb);
  k_attn<<<2048, 256, 0, stream>>>(qb, kb, vtb, pet, ctx);
  k_out<<<256, 256, 0, stream>>>(ctx, wbf + 3145728, (float*)d_out);
}